// Round 13
// baseline (269.123 us; speedup 1.0000x reference)
//
#include <hip/hip_runtime.h>
#include <stdint.h>

typedef unsigned short u16;
typedef unsigned int u32;
typedef __bf16 bf16x8 __attribute__((ext_vector_type(8)));
typedef u16 u16x8 __attribute__((ext_vector_type(8)));
typedef float f32x4 __attribute__((ext_vector_type(4)));
typedef float f32x16 __attribute__((ext_vector_type(16)));

#define NB 2
#define NS 2048
#define NE 2048
#define NH 16
#define ND 128
#define NM (NB*NS)   // 4096

__device__ __forceinline__ float bf2f(u16 u){
  union { unsigned u; float f; } v; v.u = ((unsigned)u) << 16; return v.f;
}
__device__ __forceinline__ u16 f2bf(float f){
  union { float f; unsigned u; } v; v.f = f;
  unsigned r = v.u + 0x7fffu + ((v.u >> 16) & 1u);
  return (u16)(r >> 16);
}
__device__ __forceinline__ void gl_lds16(const u16* g, u16* l){
  __builtin_amdgcn_global_load_lds((const __attribute__((address_space(1))) unsigned int*)g,
                                   (__attribute__((address_space(3))) unsigned int*)l, 16, 0, 0);
}

// ---------------- fused prep: fp32->bf16 (x + 4 weights) + RoPE tables ----------------
__global__ __launch_bounds__(256) void k_prep(const float* __restrict__ x,
                                              const float* __restrict__ w0, const float* __restrict__ w1,
                                              const float* __restrict__ w2, const float* __restrict__ w3,
                                              u16* __restrict__ xo,
                                              u16* __restrict__ o0, u16* __restrict__ o1,
                                              u16* __restrict__ o2, u16* __restrict__ o3,
                                              float* __restrict__ cosT, float* __restrict__ sinT){
  const int NX = NM * NE / 4;          // 2097152 float4
  const int NW = NE * NE / 4;          // 1048576 float4 each
  const int NC = NX + 4 * NW;          // convert items
  const int NT = NS * 64;              // table items
  const int TOT = NC + NT;
  for (int i = blockIdx.x * 256 + threadIdx.x; i < TOT; i += gridDim.x * 256){
    if (i < NC){
      const float* in; u16* out; int off;
      if (i < NX){ in = x; out = xo; off = i; }
      else {
        int j = i - NX; int sg = j >> 20; off = j & (NW - 1);
        in  = sg == 0 ? w0 : sg == 1 ? w1 : sg == 2 ? w2 : w3;
        out = sg == 0 ? o0 : sg == 1 ? o1 : sg == 2 ? o2 : o3;
      }
      float4 v = ((const float4*)in)[off];
      ushort4 o;
      o.x = f2bf(v.x); o.y = f2bf(v.y); o.z = f2bf(v.z); o.w = f2bf(v.w);
      ((ushort4*)out)[off] = o;
    } else {
      int idx = i - NC;
      int s = idx >> 6, ii = idx & 63;
      float inv = exp2f(-(float)(2 * ii) * (13.287712379549449f / 128.0f)); // 10000^(-2i/128)
      float ang = (float)s * inv;
      float c = cosf(ang), sn = sinf(ang);
      cosT[s * ND + ii]      = c;  cosT[s * ND + 64 + ii] = c;
      sinT[s * ND + ii]      = sn; sinT[s * ND + 64 + ii] = sn;
    }
  }
}

// ---------------- fused QKV GEMM: 256x256 tile, 8 waves of 128x64, BK=64, 2-buffer ----------------
// C[4096][6144] = x * [Wq;Wk;Wv]^T + b. LDS ratio: frag reads 12KB/wave/K32 (vs 16KB at
// 64x64 wave-tile) -> MfmaUtil ceiling ~64% (vs 41%). 2-barrier/kt, vmcnt(8) prefetch.
// seg 0/1: bias + RoPE epilogue -> Qa/Ka [B,H,S,D]; seg 2: bias + transpose -> Vt [B,H,D,S]
__global__ __launch_bounds__(512, 1) void k_gemm_qkv(const u16* __restrict__ A, const u16* __restrict__ Wqkv,
                                                     const float* __restrict__ bq, const float* __restrict__ bk,
                                                     const float* __restrict__ bvv,
                                                     const float* __restrict__ cosT, const float* __restrict__ sinT,
                                                     float sl, u16* __restrict__ Qa, u16* __restrict__ Ka,
                                                     u16* __restrict__ Vt)
{
  __shared__ __align__(16) u16 lds[67584];   // staging 2 x (A 16384 + B 16384) = 65536 u16; epi 256x264
  const int t    = threadIdx.x;              // 0..511
  const int lane = t & 63;
  const int g    = lane >> 4;
  const int q    = lane & 15;
  const int w    = t >> 6;                   // 0..7
  const int wr   = (w >> 2) * 128;           // 0,128
  const int wc   = (w & 3) * 64;             // 0,64,128,192

  // 384 blocks, XCD-chunked (384 % 8 == 0 -> 48/XCD)
  const int bid = blockIdx.x;
  const int v   = (bid & 7) * 48 + (bid >> 3);
  const int mi  = v / 24;
  const int ni  = v - mi * 24;
  const int bm  = mi * 256;
  const int bn  = ni * 256;

  // staging offsets: 4 chunks of 8 KiB each for A and for B (same pattern)
  int soff[4], sldo[4];
  #pragma unroll
  for (int c = 0; c < 4; ++c){
    int o = c * 8192 + t * 16;
    int row = o >> 7;
    int cb = (o & 127) ^ ((row & 7) << 4);
    sldo[c] = o >> 1;
    soff[c] = row * NE + (cb >> 1);
  }
  const u16* Abase = A    + (size_t)bm * NE;
  const u16* Wbase = Wqkv + (size_t)bn * NE;

  // fragment read byte-offsets
  int ard[2][8], brd[2][4];
  #pragma unroll
  for (int kk = 0; kk < 2; ++kk){
    #pragma unroll
    for (int m = 0; m < 8; ++m){
      int row = wr + m * 16 + q;
      ard[kk][m] = row * 128 + ((kk * 64 + g * 16) ^ ((row & 7) << 4));
    }
    #pragma unroll
    for (int n = 0; n < 4; ++n){
      int row = wc + n * 16 + q;
      brd[kk][n] = row * 128 + ((kk * 64 + g * 16) ^ ((row & 7) << 4));
    }
  }

  // prologue: stage tile 0 into buf 0 (8 loads in flight)
  #pragma unroll
  for (int c = 0; c < 4; ++c) gl_lds16(Abase + soff[c], lds + sldo[c]);
  #pragma unroll
  for (int c = 0; c < 4; ++c) gl_lds16(Wbase + soff[c], lds + 16384 + sldo[c]);

  f32x4 acc[8][4] = {};

  for (int kt = 0; kt < 32; ++kt){
    const int cbb = (kt & 1) ? 32768 : 0;
    if (kt < 31){
      const int sbb = cbb ^ 32768;
      const int go  = (kt + 1) * 64;
      #pragma unroll
      for (int c = 0; c < 4; ++c) gl_lds16(Abase + go + soff[c], lds + sbb + sldo[c]);
      #pragma unroll
      for (int c = 0; c < 4; ++c) gl_lds16(Wbase + go + soff[c], lds + sbb + 16384 + sldo[c]);
      asm volatile("s_waitcnt vmcnt(8)" ::: "memory");  // stage(kt) done; stage(kt+1) flies on
    } else {
      asm volatile("s_waitcnt vmcnt(0)" ::: "memory");
    }
    __builtin_amdgcn_s_barrier();                       // buf[kt&1] valid for all waves

    const char* Ap = (const char*)(lds + cbb);
    const char* Bp = Ap + 32768;

    #pragma unroll
    for (int kk = 0; kk < 2; ++kk){
      bf16x8 af[8], bfr[4];
      #pragma unroll
      for (int m = 0; m < 8; ++m) af[m]  = *(const bf16x8*)(Ap + ard[kk][m]);
      #pragma unroll
      for (int n = 0; n < 4; ++n) bfr[n] = *(const bf16x8*)(Bp + brd[kk][n]);
      __builtin_amdgcn_s_setprio(1);
      #pragma unroll
      for (int m = 0; m < 8; ++m)
        #pragma unroll
        for (int n = 0; n < 4; ++n)
          acc[m][n] = __builtin_amdgcn_mfma_f32_16x16x32_bf16(af[m], bfr[n], acc[m][n], 0, 0, 0);
      __builtin_amdgcn_s_setprio(0);
    }
    __builtin_amdgcn_s_barrier();                       // all reads of buf done before restage
  }

  const int seg = ni >> 3;             // 0=Q, 1=K, 2=V
  const int bnn = (ni & 7) * 256;      // column offset within the 2048-wide segment
  const int b   = bm >> 11;
  const int sbase = bm & 2047;

  if (seg == 2){
    // fused V transpose: this block owns heads h0,h0+1 x d 0..127 x s bm..bm+255
    __syncthreads();
    #pragma unroll
    for (int m = 0; m < 8; ++m)
      #pragma unroll
      for (int n = 0; n < 4; ++n){
        int cl = wc + n * 16 + q;        // 0..255 (2 heads)
        float bv = bvv[bnn + cl];
        #pragma unroll
        for (int j = 0; j < 4; ++j){
          int sl2 = wr + m * 16 + g * 4 + j;
          lds[cl * 264 + sl2] = f2bf(acc[m][n][j] + bv);
        }
      }
    __syncthreads();
    const int h0 = bnn >> 7;
    const int dq = t >> 4;           // 0..31
    const int sq = (t & 15) * 16;    // 0..240
    #pragma unroll
    for (int rep = 0; rep < 8; ++rep){
      int dd = rep * 32 + dq;        // 0..255
      int hh = dd >> 7, d = dd & 127;
      const u16* src = lds + dd * 264 + sq;
      u16* dp = Vt + ((size_t)((b * NH + h0 + hh) * ND + d)) * NS + sbase + sq;
      *(u16x8*)(dp)     = *(const u16x8*)(src);
      *(u16x8*)(dp + 8) = *(const u16x8*)(src + 8);
    }
  } else {
    // RoPE epilogue: exchange partner (d^64) through LDS tile [256][264]
    const float* bias = seg ? bk : bq;
    const float  qs   = seg ? 1.0f : sl;
    u16* out = seg ? Ka : Qa;
    __syncthreads();
    #pragma unroll
    for (int m = 0; m < 8; ++m)
      #pragma unroll
      for (int n = 0; n < 4; ++n){
        int cl = wc + n * 16 + q;
        float bv = bias[bnn + cl];
        #pragma unroll
        for (int j = 0; j < 4; ++j){
          int rl = wr + m * 16 + g * 4 + j;
          lds[rl * 264 + cl] = f2bf(acc[m][n][j] + bv);
        }
      }
    __syncthreads();
    #pragma unroll
    for (int m = 0; m < 8; ++m)
      #pragma unroll
      for (int n = 0; n < 4; ++n){
        int cl  = wc + n * 16 + q;       // 0..255 (2 heads)
        int col = bnn + cl;
        int h  = col >> 7;
        int dd = col & 127;
        float bv = bias[col];
        #pragma unroll
        for (int j = 0; j < 4; ++j){
          int rl = wr + m * 16 + g * 4 + j;
          int s = sbase + rl;
          float mine    = acc[m][n][j] + bv;
          float partner = bf2f(lds[rl * 264 + (cl ^ 64)]);   // same head: ^64 stays in 128-block
          float rot = (dd < 64) ? -partner : partner;
          float val = (mine * cosT[s * ND + dd] + rot * sinT[s * ND + dd]) * qs;
          out[(((size_t)(b * NH + h)) * NS + s) * ND + dd] = f2bf(val);
        }
      }
  }
}

// ---------------- output GEMM (round-12 proven 3-buffer): d_out = ctx * Wo^T + bo ----------------
__global__ __launch_bounds__(512, 2) void k_gemm_o(const u16* __restrict__ A, const u16* __restrict__ W,
                                                   const float* __restrict__ bias, float* __restrict__ out)
{
  __shared__ __align__(16) u16 lds[73728];   // 3 x (A 16384 + B 8192) u16 = 144 KiB
  const int t    = threadIdx.x;
  const int lane = t & 63;
  const int g    = lane >> 4;
  const int q    = lane & 15;
  const int wid  = t >> 6;
  const int wr   = (wid >> 1) * 64;
  const int wc   = (wid & 1) * 64;
  const int bid = blockIdx.x;
  const int v   = (bid & 7) * 32 + (bid >> 3);
  const int bm  = (v >> 4) * 256;
  const int bn  = (v & 15) * 128;

  int aoff[4], aldso[4], boff[2], bldso[2];
  #pragma unroll
  for (int c = 0; c < 4; ++c){
    int o = c * 8192 + t * 16;
    int row = o >> 7;
    int cb2 = (o & 127) ^ ((row & 7) << 4);
    aldso[c] = o >> 1;
    aoff[c]  = row * NE + (cb2 >> 1);
  }
  #pragma unroll
  for (int c = 0; c < 2; ++c){
    int o = c * 8192 + t * 16;
    int row = o >> 7;
    int cb2 = (o & 127) ^ ((row & 7) << 4);
    bldso[c] = o >> 1;
    boff[c]  = row * NE + (cb2 >> 1);
  }
  const u16* Abase = A + (size_t)bm * NE;
  const u16* Wbase = W + (size_t)bn * NE;

  int ard[2][4], brd[2][4];
  #pragma unroll
  for (int kk = 0; kk < 2; ++kk){
    #pragma unroll
    for (int m = 0; m < 4; ++m){
      int row = wr + m * 16 + q;
      ard[kk][m] = row * 128 + ((kk * 64 + g * 16) ^ ((row & 7) << 4));
    }
    #pragma unroll
    for (int n = 0; n < 4; ++n){
      int row = wc + n * 16 + q;
      brd[kk][n] = row * 128 + ((kk * 64 + g * 16) ^ ((row & 7) << 4));
    }
  }

  #pragma unroll
  for (int c = 0; c < 4; ++c) gl_lds16(Abase + aoff[c], lds + aldso[c]);
  #pragma unroll
  for (int c = 0; c < 2; ++c) gl_lds16(Wbase + boff[c], lds + 16384 + bldso[c]);

  f32x4 acc[4][4] = {};
  int cbb = 0, sbb = 24576;
  for (int kt = 0; kt < 32; ++kt){
    if (kt < 31){
      const int go = (kt + 1) * 64;
      #pragma unroll
      for (int c = 0; c < 4; ++c) gl_lds16(Abase + go + aoff[c], lds + sbb + aldso[c]);
      #pragma unroll
      for (int c = 0; c < 2; ++c) gl_lds16(Wbase + go + boff[c], lds + sbb + 16384 + bldso[c]);
      asm volatile("s_waitcnt vmcnt(6)" ::: "memory");
    } else {
      asm volatile("s_waitcnt vmcnt(0)" ::: "memory");
    }
    __builtin_amdgcn_s_barrier();
    const char* Ap = (const char*)(lds + cbb);
    const char* Bp = (const char*)(lds + cbb + 16384);
    #pragma unroll
    for (int kk = 0; kk < 2; ++kk){
      bf16x8 af[4], bfr[4];
      #pragma unroll
      for (int m = 0; m < 4; ++m) af[m]  = *(const bf16x8*)(Ap + ard[kk][m]);
      #pragma unroll
      for (int n = 0; n < 4; ++n) bfr[n] = *(const bf16x8*)(Bp + brd[kk][n]);
      __builtin_amdgcn_s_setprio(1);
      #pragma unroll
      for (int m = 0; m < 4; ++m)
        #pragma unroll
        for (int n = 0; n < 4; ++n)
          acc[m][n] = __builtin_amdgcn_mfma_f32_16x16x32_bf16(af[m], bfr[n], acc[m][n], 0, 0, 0);
      __builtin_amdgcn_s_setprio(0);
    }
    cbb = (cbb == 49152) ? 0 : cbb + 24576;
    sbb = (sbb == 49152) ? 0 : sbb + 24576;
  }

  #pragma unroll
  for (int m = 0; m < 4; ++m)
    #pragma unroll
    for (int n = 0; n < 4; ++n){
      int col = bn + wc + n * 16 + q;
      float bv = bias[col];
      #pragma unroll
      for (int j = 0; j < 4; ++j){
        int row = bm + wr + m * 16 + g * 4 + j;
        out[(size_t)row * NE + col] = acc[m][n][j] + bv;
      }
    }
}

// ---------------- Flash attention: static-max softmax, pipelined QKT(kt+1) ----------------
template<bool D1>
__device__ __forceinline__ void pswap(u32 &a, u32 &b){
  if constexpr (D1) asm volatile("v_permlane32_swap_b32 %0, %1" : "+v"(a), "+v"(b));
  else              asm volatile("v_permlane32_swap_b32 %0, %1" : "+v"(b), "+v"(a));
}

#define AT_BODY(KT, SCC, SCN, KSTG, VSTG, KNXT, VCUR, SK, SV, VM, LAST)               \
  {                                                                                   \
    if (SK){ const int kb = ((KT) + 2) * 64 * ND;                                     \
      _Pragma("unroll") for (int c = 0; c < 4; ++c)                                   \
        gl_lds16(Kbase + kb + koff[c], (KSTG) + kldso[c]); }                          \
    if (SV){ const int vb = ((KT) + 1) * 64;                                          \
      _Pragma("unroll") for (int c = 0; c < 4; ++c)                                   \
        gl_lds16(Vbase + vb + voff[c], (VSTG) + vldso[c]); }                          \
    asm volatile("s_waitcnt vmcnt(" VM ")" ::: "memory");                             \
    __builtin_amdgcn_s_barrier();                                                     \
    float ts = 0.f;                                                                   \
    if (!(LAST)){                                                                     \
      SCN[0] = (f32x16)(0.f);                                                         \
      __builtin_amdgcn_s_setprio(1);                                                  \
      _Pragma("unroll") for (int kk = 0; kk < 8; ++kk){                               \
        bf16x8 kf = *(const bf16x8*)((KNXT) + krd[0][kk]);                            \
        SCN[0] = __builtin_amdgcn_mfma_f32_32x32x16_bf16(kf, qf[kk], SCN[0], 0, 0, 0);\
      }                                                                               \
      __builtin_amdgcn_s_setprio(0);                                                  \
    }                                                                                 \
    _Pragma("unroll") for (int r = 0; r < 16; ++r){                                   \
      float e = exp2f(SCC[0][r]); SCC[0][r] = e; ts += e; }                           \
    if (!(LAST)){                                                                     \
      SCN[1] = (f32x16)(0.f);                                                         \
      __builtin_amdgcn_s_setprio(1);                                                  \
      _Pragma("unroll") for (int kk = 0; kk < 8; ++kk){                               \
        bf16x8 kf = *(const bf16x8*)((KNXT) + krd[1][kk]);                            \
        SCN[1] = __builtin_amdgcn_mfma_f32_32x32x16_bf16(kf, qf[kk], SCN[1], 0, 0, 0);\
      }                                                                               \
      __builtin_amdgcn_s_setprio(0);                                                  \
    }                                                                                 \
    _Pragma("unroll") for (int r = 0; r < 16; ++r){                                   \
      float e = exp2f(SCC[1][r]); SCC[1][r] = e; ts += e; }                           \
    lrow += ts;                                                                       \
    __builtin_amdgcn_s_setprio(1);                                                    \
    _Pragma("unroll") for (int t2 = 0; t2 < 2; ++t2)                                  \
      _Pragma("unroll") for (int kk2 = 0; kk2 < 2; ++kk2){                            \
        u32 a0, a1, b0, b1;                                                           \
        asm("v_cvt_pk_bf16_f32 %0, %1, %2" : "=v"(a0) : "v"(SCC[t2][8*kk2+0]), "v"(SCC[t2][8*kk2+1])); \
        asm("v_cvt_pk_bf16_f32 %0, %1, %2" : "=v"(a1) : "v"(SCC[t2][8*kk2+2]), "v"(SCC[t2][8*kk2+3])); \
        asm("v_cvt_pk_bf16_f32 %0, %1, %2" : "=v"(b0) : "v"(SCC[t2][8*kk2+4]), "v"(SCC[t2][8*kk2+5])); \
        asm("v_cvt_pk_bf16_f32 %0, %1, %2" : "=v"(b1) : "v"(SCC[t2][8*kk2+6]), "v"(SCC[t2][8*kk2+7])); \
        pswap<D1>(a0, b0); pswap<D1>(a1, b1);                                         \
        union { u32 u[4]; bf16x8 v; } pf;                                             \
        pf.u[0] = a0; pf.u[1] = a1; pf.u[2] = b0; pf.u[3] = b1;                       \
        const int kkf = 2*t2 + kk2;                                                   \
        _Pragma("unroll") for (int dt = 0; dt < 4; ++dt){                             \
          bf16x8 vf = *(const bf16x8*)((VCUR) + vrd[kkf][dt]);                        \
          acc[dt] = __builtin_amdgcn_mfma_f32_32x32x16_bf16(vf, pf.v, acc[dt], 0, 0, 0); \
        }                                                                             \
      }                                                                               \
    __builtin_amdgcn_s_setprio(0);                                                    \
    if (!(LAST)) __builtin_amdgcn_s_barrier();                                        \
  }

template<bool D1>
__device__ __forceinline__ void attn_impl(const u16* __restrict__ Qa, const u16* __restrict__ Ka,
                                          const u16* __restrict__ Vt, u16* __restrict__ ctx,
                                          u16* Ks0, u16* Ks1, u16* Vs0, u16* Vs1)
{
  const int t    = threadIdx.x;
  const int lane = t & 63;
  const int w    = t >> 6;
  const int l31  = lane & 31;
  const int hi   = lane >> 5;

  const int v   = (blockIdx.x & 7) * 64 + (blockIdx.x >> 3);   // XCD-chunked swizzle
  const int qb  = v & 15;
  const int bh  = v >> 4;
  const int q0  = qb * 128 + w * 32;

  int koff[4], kldso[4], voff[4], vldso[4];
  #pragma unroll
  for (int c = 0; c < 4; ++c){
    int o = c * 4096 + t * 16;
    { int row = o >> 8, col = o & 255; int cs = col ^ ((row & 15) << 4);
      kldso[c] = o >> 1;  koff[c] = row * ND + (cs >> 1); }
    { int row = o >> 7, col = o & 127; int cs = col ^ ((row & 7) << 4);
      vldso[c] = o >> 1;  voff[c] = row * NS + (cs >> 1); }
  }
  const u16* Kbase = Ka + (size_t)bh * NS * ND;
  const u16* Vbase = Vt + (size_t)bh * ND * NS;

  // Q fragments first (8 vmem), then stage K0, V0, K1 (12 vmem)
  bf16x8 qf[8];
  #pragma unroll
  for (int kk = 0; kk < 8; ++kk)
    qf[kk] = *(const bf16x8*)(Qa + ((size_t)bh * NS + q0 + l31) * ND + kk * 16 + hi * 8);

  #pragma unroll
  for (int c = 0; c < 4; ++c) gl_lds16(Kbase + koff[c], Ks0 + kldso[c]);
  #pragma unroll
  for (int c = 0; c < 4; ++c) gl_lds16(Vbase + voff[c], Vs0 + vldso[c]);
  #pragma unroll
  for (int c = 0; c < 4; ++c) gl_lds16(Kbase + 64 * ND + koff[c], Ks1 + kldso[c]);

  // hoisted LDS read byte-offsets
  int krd[2][8], vrd[4][4];
  #pragma unroll
  for (int t2 = 0; t2 < 2; ++t2){
    const int row = t2 * 32 + l31, sw = (row & 15) << 4;
    #pragma unroll
    for (int kk = 0; kk < 8; ++kk)
      krd[t2][kk] = row * 256 + ((kk * 32 + hi * 16) ^ sw);
  }
  #pragma unroll
  for (int dt = 0; dt < 4; ++dt){
    const int row = dt * 32 + l31, sw = (row & 7) << 4;
    #pragma unroll
    for (int kk = 0; kk < 4; ++kk)
      vrd[kk][dt] = row * 128 + ((kk * 32 + hi * 16) ^ sw);
  }

  asm volatile("s_waitcnt vmcnt(8)" ::: "memory");   // qf + K0 done; V0,K1 in flight
  __builtin_amdgcn_s_barrier();

  f32x16 scA[2], scB[2];
  scA[0] = (f32x16)(0.f); scA[1] = (f32x16)(0.f);
  {
    const char* Kl = (const char*)Ks0;
    #pragma unroll
    for (int t2 = 0; t2 < 2; ++t2)
      #pragma unroll
      for (int kk = 0; kk < 8; ++kk){
        bf16x8 kf = *(const bf16x8*)(Kl + krd[t2][kk]);
        scA[t2] = __builtin_amdgcn_mfma_f32_32x32x16_bf16(kf, qf[kk], scA[t2], 0, 0, 0);
      }
  }
  __builtin_amdgcn_s_barrier();   // K0 buffer free for restaging

  f32x16 acc[4] = {};
  float lrow = 0.f;

  for (int kt = 0; kt < 30; kt += 2){
    AT_BODY(kt,     scA, scB, Ks0, Vs1, (const char*)Ks1, (const char*)Vs0, 1, 1, "8", 0);
    AT_BODY(kt + 1, scB, scA, Ks1, Vs0, (const char*)Ks0, (const char*)Vs1, 1, 1, "8", 0);
  }
  AT_BODY(30, scA, scB, Ks0, Vs1, (const char*)Ks1, (const char*)Vs0, 0, 1, "4", 0);
  AT_BODY(31, scB, scA, Ks1, Vs0, (const char*)Ks0, (const char*)Vs1, 0, 0, "0", 1);

  // epilogue: one cross-half reduce of lrow, then O[q][d] = acc / l -> ctx [B][S][E]
  lrow += __shfl_xor(lrow, 32);
  const float inv = 1.0f / lrow;
  const int b = bh >> 4, h = bh & 15;
  const int s = q0 + l31;
  #pragma unroll
  for (int dt = 0; dt < 4; ++dt)
    #pragma unroll
    for (int a2 = 0; a2 < 4; ++a2){
      const int d0 = dt * 32 + 8 * a2 + 4 * hi;
      ushort4 o;
      o.x = f2bf(acc[dt][4*a2+0] * inv);
      o.y = f2bf(acc[dt][4*a2+1] * inv);
      o.z = f2bf(acc[dt][4*a2+2] * inv);
      o.w = f2bf(acc[dt][4*a2+3] * inv);
      *(ushort4*)(ctx + ((size_t)(b * NS + s)) * NE + h * ND + d0) = o;
    }
}

__global__ __launch_bounds__(256, 2) void k_attn(const u16* __restrict__ Qa, const u16* __restrict__ Ka,
                                                 const u16* __restrict__ Vt, u16* __restrict__ ctx)
{
  __shared__ __align__(16) u16 Ks[2][64 * 128];  // [kv][d], 256B rows, swz (row&15)<<4
  __shared__ __align__(16) u16 Vs[2][128 * 64];  // [d][kv], 128B rows, swz (row&7)<<4
  // runtime probe of v_permlane32_swap_b32 direction (wave-uniform)
  const int lane = threadIdx.x & 63;
  u32 xx = (u32)lane, yy = 64u + (u32)lane;
  asm volatile("v_permlane32_swap_b32 %0, %1" : "+v"(xx), "+v"(yy));
  const bool isD1 = (xx == (u32)(lane < 32 ? lane : lane + 32));
  if (isD1) attn_impl<true >(Qa, Ka, Vt, ctx, &Ks[0][0], &Ks[1][0], &Vs[0][0], &Vs[1][0]);
  else      attn_impl<false>(Qa, Ka, Vt, ctx, &Ks[0][0], &Ks[1][0], &Vs[0][0], &Vs[1][0]);
}

extern "C" void kernel_launch(void* const* d_in, const int* in_sizes, int n_in,
                              void* d_out, int out_size, void* d_ws, size_t ws_size,
                              hipStream_t stream)
{
  const float* x  = (const float*)d_in[0];
  const float* Wq = (const float*)d_in[1];
  const float* bq = (const float*)d_in[2];
  const float* Wk = (const float*)d_in[3];
  const float* bk = (const float*)d_in[4];
  const float* Wv = (const float*)d_in[5];
  const float* bv = (const float*)d_in[6];
  const float* Wo = (const float*)d_in[7];
  const float* bo = (const float*)d_in[8];

  char* ws = (char*)d_ws;
  u16*   xbf  = (u16*)(ws);                      // 16 MiB
  u16*   wqb  = (u16*)(ws + 16777216);           // 8 MiB each; wq,wk,wv CONTIGUOUS (fused W)
  u16*   wkb  = (u16*)(ws + 25165824);
  u16*   wvb  = (u16*)(ws + 33554432);
  u16*   wob  = (u16*)(ws + 41943040);
  float* cosT = (float*)(ws + 50331648);         // 1 MiB each
  float* sinT = (float*)(ws + 51380224);
  u16*   Qa   = (u16*)(ws + 52428800);           // 16 MiB
  u16*   Ka   = (u16*)(ws + 69206016);           // 16 MiB
  u16*   Vt   = (u16*)(ws + 85983232);           // 16 MiB, written transposed by k_gemm_qkv
  u16*   ctx  = xbf;   // alias: x dead after the projection GEMM

  const float sl = 0.08838834764831845f * 1.4426950408889634f;  // (1/sqrt(128)) * log2(e)

  k_prep<<<2048, 256, 0, stream>>>(x, Wq, Wk, Wv, Wo, xbf, wqb, wkb, wvb, wob, cosT, sinT);

  k_gemm_qkv<<<384, 512, 0, stream>>>(xbf, wqb, bq, bk, bv, cosT, sinT, sl, Qa, Ka, Vt);

  k_attn<<<512, 256, 0, stream>>>(Qa, Ka, Vt, ctx);

  k_gemm_o<<<256, 512, 0, stream>>>(ctx, wob, bo, (float*)d_out);
}

// Round 14
// 254.457 us; speedup vs baseline: 1.0576x; 1.0576x over previous
//
#include <hip/hip_runtime.h>
#include <stdint.h>

typedef unsigned short u16;
typedef unsigned int u32;
typedef __bf16 bf16x8 __attribute__((ext_vector_type(8)));
typedef u16 u16x8 __attribute__((ext_vector_type(8)));
typedef float f32x4 __attribute__((ext_vector_type(4)));
typedef float f32x16 __attribute__((ext_vector_type(16)));

#define NB 2
#define NS 2048
#define NE 2048
#define NH 16
#define ND 128
#define NM (NB*NS)   // 4096

__device__ __forceinline__ float bf2f(u16 u){
  union { unsigned u; float f; } v; v.u = ((unsigned)u) << 16; return v.f;
}
__device__ __forceinline__ u16 f2bf(float f){
  union { float f; unsigned u; } v; v.f = f;
  unsigned r = v.u + 0x7fffu + ((v.u >> 16) & 1u);
  return (u16)(r >> 16);
}
__device__ __forceinline__ void gl_lds16(const u16* g, u16* l){
  __builtin_amdgcn_global_load_lds((const __attribute__((address_space(1))) unsigned int*)g,
                                   (__attribute__((address_space(3))) unsigned int*)l, 16, 0, 0);
}

// ---------------- fused prep: fp32->bf16 (x + 4 weights) + RoPE tables ----------------
__global__ __launch_bounds__(256) void k_prep(const float* __restrict__ x,
                                              const float* __restrict__ w0, const float* __restrict__ w1,
                                              const float* __restrict__ w2, const float* __restrict__ w3,
                                              u16* __restrict__ xo,
                                              u16* __restrict__ o0, u16* __restrict__ o1,
                                              u16* __restrict__ o2, u16* __restrict__ o3,
                                              float* __restrict__ cosT, float* __restrict__ sinT){
  const int NX = NM * NE / 4;          // 2097152 float4
  const int NW = NE * NE / 4;          // 1048576 float4 each
  const int NC = NX + 4 * NW;          // convert items
  const int NT = NS * 64;              // table items
  const int TOT = NC + NT;
  for (int i = blockIdx.x * 256 + threadIdx.x; i < TOT; i += gridDim.x * 256){
    if (i < NC){
      const float* in; u16* out; int off;
      if (i < NX){ in = x; out = xo; off = i; }
      else {
        int j = i - NX; int sg = j >> 20; off = j & (NW - 1);
        in  = sg == 0 ? w0 : sg == 1 ? w1 : sg == 2 ? w2 : w3;
        out = sg == 0 ? o0 : sg == 1 ? o1 : sg == 2 ? o2 : o3;
      }
      float4 v = ((const float4*)in)[off];
      ushort4 o;
      o.x = f2bf(v.x); o.y = f2bf(v.y); o.z = f2bf(v.z); o.w = f2bf(v.w);
      ((ushort4*)out)[off] = o;
    } else {
      int idx = i - NC;
      int s = idx >> 6, ii = idx & 63;
      float inv = exp2f(-(float)(2 * ii) * (13.287712379549449f / 128.0f)); // 10000^(-2i/128)
      float ang = (float)s * inv;
      float c = cosf(ang), sn = sinf(ang);
      cosT[s * ND + ii]      = c;  cosT[s * ND + 64 + ii] = c;
      sinT[s * ND + ii]      = sn; sinT[s * ND + 64 + ii] = sn;
    }
  }
}

// ================= shared GEMM K-loop (3-buffer, 1 barrier/K-tile) — round-12 proven =================
#define GEMM_PREAMBLE                                                                 \
  const int t    = threadIdx.x;                                                      \
  const int lane = t & 63;                                                           \
  const int g    = lane >> 4;                                                        \
  const int q    = lane & 15;                                                        \
  const int wid  = t >> 6;                                                           \
  const int wr   = (wid >> 1) * 64;                                                  \
  const int wc   = (wid & 1) * 64;                                                   \
  int aoff[4], aldso[4], boff[2], bldso[2];                                          \
  _Pragma("unroll") for (int c = 0; c < 4; ++c){                                     \
    int o = c * 8192 + t * 16;                                                       \
    int row = o >> 7;                                                                \
    int cb2 = (o & 127) ^ ((row & 7) << 4);                                          \
    aldso[c] = o >> 1;                                                               \
    aoff[c]  = row * NE + (cb2 >> 1);                                                \
  }                                                                                  \
  _Pragma("unroll") for (int c = 0; c < 2; ++c){                                     \
    int o = c * 8192 + t * 16;                                                       \
    int row = o >> 7;                                                                \
    int cb2 = (o & 127) ^ ((row & 7) << 4);                                          \
    bldso[c] = o >> 1;                                                               \
    boff[c]  = row * NE + (cb2 >> 1);                                                \
  }                                                                                  \
  int ard[2][4], brd[2][4];                                                          \
  _Pragma("unroll") for (int kk = 0; kk < 2; ++kk){                                  \
    _Pragma("unroll") for (int m = 0; m < 4; ++m){                                   \
      int row = wr + m * 16 + q;                                                     \
      ard[kk][m] = row * 128 + ((kk * 64 + g * 16) ^ ((row & 7) << 4));              \
    }                                                                                \
    _Pragma("unroll") for (int n = 0; n < 4; ++n){                                   \
      int row = wc + n * 16 + q;                                                     \
      brd[kk][n] = row * 128 + ((kk * 64 + g * 16) ^ ((row & 7) << 4));              \
    }                                                                                \
  }

#define GEMM_KLOOP(Abase, Wbase, lds)                                                \
  _Pragma("unroll") for (int c = 0; c < 4; ++c) gl_lds16((Abase) + aoff[c], (lds) + aldso[c]); \
  _Pragma("unroll") for (int c = 0; c < 2; ++c) gl_lds16((Wbase) + boff[c], (lds) + 16384 + bldso[c]); \
  f32x4 acc[4][4] = {};                                                              \
  int cbb = 0, sbb = 24576;                                                          \
  for (int kt = 0; kt < 32; ++kt){                                                   \
    if (kt < 31){                                                                    \
      const int go = (kt + 1) * 64;                                                  \
      _Pragma("unroll") for (int c = 0; c < 4; ++c) gl_lds16((Abase) + go + aoff[c], (lds) + sbb + aldso[c]); \
      _Pragma("unroll") for (int c = 0; c < 2; ++c) gl_lds16((Wbase) + go + boff[c], (lds) + sbb + 16384 + bldso[c]); \
      asm volatile("s_waitcnt vmcnt(6)" ::: "memory");                               \
    } else {                                                                         \
      asm volatile("s_waitcnt vmcnt(0)" ::: "memory");                               \
    }                                                                                \
    __builtin_amdgcn_s_barrier();                                                    \
    const char* Ap = (const char*)((lds) + cbb);                                     \
    const char* Bp = (const char*)((lds) + cbb + 16384);                             \
    _Pragma("unroll") for (int kk = 0; kk < 2; ++kk){                                \
      bf16x8 af[4], bfr[4];                                                          \
      _Pragma("unroll") for (int m = 0; m < 4; ++m) af[m]  = *(const bf16x8*)(Ap + ard[kk][m]); \
      _Pragma("unroll") for (int n = 0; n < 4; ++n) bfr[n] = *(const bf16x8*)(Bp + brd[kk][n]); \
      __builtin_amdgcn_s_setprio(1);                                                 \
      _Pragma("unroll") for (int m = 0; m < 4; ++m)                                  \
        _Pragma("unroll") for (int n = 0; n < 4; ++n)                                \
          acc[m][n] = __builtin_amdgcn_mfma_f32_16x16x32_bf16(af[m], bfr[n], acc[m][n], 0, 0, 0); \
      __builtin_amdgcn_s_setprio(0);                                                 \
    }                                                                                \
    cbb = (cbb == 49152) ? 0 : cbb + 24576;                                          \
    sbb = (sbb == 49152) ? 0 : sbb + 24576;                                          \
  }

// ---------------- fused QKV GEMM: C[4096][6144] = x * [Wq;Wk;Wv]^T + b ----------------
__global__ __launch_bounds__(512, 2) void k_gemm_qkv(const u16* __restrict__ A, const u16* __restrict__ Wqkv,
                                                     const float* __restrict__ bq, const float* __restrict__ bk,
                                                     const float* __restrict__ bvv,
                                                     const float* __restrict__ cosT, const float* __restrict__ sinT,
                                                     float sl, u16* __restrict__ Qa, u16* __restrict__ Ka,
                                                     u16* __restrict__ Vt)
{
  __shared__ __align__(16) u16 lds[73728];   // 3 x (A 16384 + B 8192) u16 = 144 KiB
  GEMM_PREAMBLE
  // 768 blocks, XCD-chunked (768 % 8 == 0, cpx = 96)
  const int bid = blockIdx.x;
  const int v   = (bid & 7) * 96 + (bid >> 3);
  const int mi  = v / 48;
  const int ni  = v - mi * 48;
  const int bm  = mi * 256;
  const int bn  = ni * 128;

  const u16* Abase = A    + (size_t)bm * NE;
  const u16* Wbase = Wqkv + (size_t)bn * NE;

  GEMM_KLOOP(Abase, Wbase, lds)

  const int seg = bn >> 11;      // 0=Q, 1=K, 2=V
  const int bnn = bn & 2047;
  if (seg == 2){
    // fused V transpose: this block owns Vt[bh][d=0..127][s=bm..bm+255]
    const float* bias = bvv;
    __syncthreads();
    #pragma unroll
    for (int m = 0; m < 4; ++m)
      #pragma unroll
      for (int n = 0; n < 4; ++n){
        int d = wc + n * 16 + q;
        float bv = bias[bnn + d];
        #pragma unroll
        for (int j = 0; j < 4; ++j){
          int sl2 = wr + m * 16 + g * 4 + j;
          lds[d * 264 + sl2] = f2bf(acc[m][n][j] + bv);
        }
      }
    __syncthreads();
    const int b = bm >> 11, h = bnn >> 7, sbase = bm & 2047;
    const int dq = t >> 4;           // 0..31
    const int sq = (t & 15) * 16;    // 0..240
    #pragma unroll
    for (int rep = 0; rep < 4; ++rep){
      int d = rep * 32 + dq;
      const u16* src = lds + d * 264 + sq;
      u16* dp = Vt + ((size_t)((b * NH + h) * ND + d)) * NS + sbase + sq;
      *(u16x8*)(dp)     = *(const u16x8*)(src);
      *(u16x8*)(dp + 8) = *(const u16x8*)(src + 8);
    }
  } else {
    // RoPE epilogue: exchange partner (d^64) through LDS tile [256][132]
    const float* bias = seg ? bk : bq;
    const float  qs   = seg ? 1.0f : sl;
    u16* out = seg ? Ka : Qa;
    __syncthreads();
    #pragma unroll
    for (int m = 0; m < 4; ++m)
      #pragma unroll
      for (int n = 0; n < 4; ++n){
        int cl = wc + n * 16 + q;
        float bv = bias[bnn + cl];
        #pragma unroll
        for (int j = 0; j < 4; ++j){
          int rl = wr + m * 16 + g * 4 + j;
          lds[rl * 132 + cl] = f2bf(acc[m][n][j] + bv);
        }
      }
    __syncthreads();
    #pragma unroll
    for (int m = 0; m < 4; ++m)
      #pragma unroll
      for (int n = 0; n < 4; ++n){
        int cl  = wc + n * 16 + q;
        int col = bnn + cl;
        int h = col >> 7;
        float bv = bias[col];
        #pragma unroll
        for (int j = 0; j < 4; ++j){
          int rl = wr + m * 16 + g * 4 + j;
          int row = bm + rl;
          int b = row >> 11, s = row & 2047;
          float mine    = acc[m][n][j] + bv;
          float partner = bf2f(lds[rl * 132 + (cl ^ 64)]);
          float rot = (cl < 64) ? -partner : partner;
          float val = (mine * cosT[s * ND + cl] + rot * sinT[s * ND + cl]) * qs;
          out[(((size_t)(b * NH + h)) * NS + s) * ND + cl] = f2bf(val);
        }
      }
  }
}

// ---------------- output GEMM: d_out[4096][2048] fp32 = ctx * Wo^T + bo ----------------
__global__ __launch_bounds__(512, 2) void k_gemm_o(const u16* __restrict__ A, const u16* __restrict__ W,
                                                   const float* __restrict__ bias, float* __restrict__ out)
{
  __shared__ __align__(16) u16 lds[73728];
  GEMM_PREAMBLE
  const int bid = blockIdx.x;
  const int v   = (bid & 7) * 32 + (bid >> 3);
  const int bm  = (v >> 4) * 256;
  const int bn  = (v & 15) * 128;

  const u16* Abase = A + (size_t)bm * NE;
  const u16* Wbase = W + (size_t)bn * NE;

  GEMM_KLOOP(Abase, Wbase, lds)

  #pragma unroll
  for (int m = 0; m < 4; ++m)
    #pragma unroll
    for (int n = 0; n < 4; ++n){
      int col = bn + wc + n * 16 + q;
      float bv = bias[col];
      #pragma unroll
      for (int j = 0; j < 4; ++j){
        int row = bm + wr + m * 16 + g * 4 + j;
        out[(size_t)row * NE + col] = acc[m][n][j] + bv;
      }
    }
}

// ---------------- Flash attention: 8-wave blocks (q-tile 256), 16 waves/CU, static-max softmax ----------------
template<bool D1>
__device__ __forceinline__ void pswap(u32 &a, u32 &b){
  if constexpr (D1) asm volatile("v_permlane32_swap_b32 %0, %1" : "+v"(a), "+v"(b));
  else              asm volatile("v_permlane32_swap_b32 %0, %1" : "+v"(b), "+v"(a));
}

// vmem FIFO ledger (2-load chunks): per body issue K(kt+2)x2 + V(kt+1)x2.
// At body kt the oldest 4 outstanding are exactly {K(kt+1)x2, V(kt)x2} -> vmcnt(4)
// retires precisely what this body reads (QKT(kt+1) from LDS K, PV(kt) from LDS V).
#define AT_BODY(KT, SCC, SCN, KSTG, VSTG, KNXT, VCUR, SK, SV, VM, LAST)               \
  {                                                                                   \
    if (SK){ const int kb = ((KT) + 2) * 64 * ND;                                     \
      _Pragma("unroll") for (int c = 0; c < 2; ++c)                                   \
        gl_lds16(Kbase + kb + koff[c], (KSTG) + kldso[c]); }                          \
    if (SV){ const int vb = ((KT) + 1) * 64;                                          \
      _Pragma("unroll") for (int c = 0; c < 2; ++c)                                   \
        gl_lds16(Vbase + vb + voff[c], (VSTG) + vldso[c]); }                          \
    asm volatile("s_waitcnt vmcnt(" VM ")" ::: "memory");                             \
    __builtin_amdgcn_s_barrier();                                                     \
    float ts = 0.f;                                                                   \
    if (!(LAST)){                                                                     \
      SCN[0] = (f32x16)(0.f);                                                         \
      __builtin_amdgcn_s_setprio(1);                                                  \
      _Pragma("unroll") for (int kk = 0; kk < 8; ++kk){                               \
        bf16x8 kf = *(const bf16x8*)((KNXT) + krd[0][kk]);                            \
        SCN[0] = __builtin_amdgcn_mfma_f32_32x32x16_bf16(kf, qf[kk], SCN[0], 0, 0, 0);\
      }                                                                               \
      __builtin_amdgcn_s_setprio(0);                                                  \
    }                                                                                 \
    _Pragma("unroll") for (int r = 0; r < 16; ++r){                                   \
      float e = exp2f(SCC[0][r]); SCC[0][r] = e; ts += e; }                           \
    if (!(LAST)){                                                                     \
      SCN[1] = (f32x16)(0.f);                                                         \
      __builtin_amdgcn_s_setprio(1);                                                  \
      _Pragma("unroll") for (int kk = 0; kk < 8; ++kk){                               \
        bf16x8 kf = *(const bf16x8*)((KNXT) + krd[1][kk]);                            \
        SCN[1] = __builtin_amdgcn_mfma_f32_32x32x16_bf16(kf, qf[kk], SCN[1], 0, 0, 0);\
      }                                                                               \
      __builtin_amdgcn_s_setprio(0);                                                  \
    }                                                                                 \
    _Pragma("unroll") for (int r = 0; r < 16; ++r){                                   \
      float e = exp2f(SCC[1][r]); SCC[1][r] = e; ts += e; }                           \
    lrow += ts;                                                                       \
    __builtin_amdgcn_s_setprio(1);                                                    \
    _Pragma("unroll") for (int t2 = 0; t2 < 2; ++t2)                                  \
      _Pragma("unroll") for (int kk2 = 0; kk2 < 2; ++kk2){                            \
        u32 a0, a1, b0, b1;                                                           \
        asm("v_cvt_pk_bf16_f32 %0, %1, %2" : "=v"(a0) : "v"(SCC[t2][8*kk2+0]), "v"(SCC[t2][8*kk2+1])); \
        asm("v_cvt_pk_bf16_f32 %0, %1, %2" : "=v"(a1) : "v"(SCC[t2][8*kk2+2]), "v"(SCC[t2][8*kk2+3])); \
        asm("v_cvt_pk_bf16_f32 %0, %1, %2" : "=v"(b0) : "v"(SCC[t2][8*kk2+4]), "v"(SCC[t2][8*kk2+5])); \
        asm("v_cvt_pk_bf16_f32 %0, %1, %2" : "=v"(b1) : "v"(SCC[t2][8*kk2+6]), "v"(SCC[t2][8*kk2+7])); \
        pswap<D1>(a0, b0); pswap<D1>(a1, b1);                                         \
        union { u32 u[4]; bf16x8 v; } pf;                                             \
        pf.u[0] = a0; pf.u[1] = a1; pf.u[2] = b0; pf.u[3] = b1;                       \
        const int kkf = 2*t2 + kk2;                                                   \
        _Pragma("unroll") for (int dt = 0; dt < 4; ++dt){                             \
          bf16x8 vf = *(const bf16x8*)((VCUR) + vrd[kkf][dt]);                        \
          acc[dt] = __builtin_amdgcn_mfma_f32_32x32x16_bf16(vf, pf.v, acc[dt], 0, 0, 0); \
        }                                                                             \
      }                                                                               \
    __builtin_amdgcn_s_setprio(0);                                                    \
    if (!(LAST)) __builtin_amdgcn_s_barrier();                                        \
  }

template<bool D1>
__device__ __forceinline__ void attn_impl(const u16* __restrict__ Qa, const u16* __restrict__ Ka,
                                          const u16* __restrict__ Vt, u16* __restrict__ ctx,
                                          u16* Ks0, u16* Ks1, u16* Vs0, u16* Vs1)
{
  const int t    = threadIdx.x;      // 0..511
  const int lane = t & 63;
  const int w    = t >> 6;           // 0..7
  const int l31  = lane & 31;
  const int hi   = lane >> 5;

  // 256 blocks XCD-chunked; unit = bh*8 + qb
  const int v   = (blockIdx.x & 7) * 32 + (blockIdx.x >> 3);
  const int qb  = v & 7;
  const int bh  = v >> 3;
  const int q0  = qb * 256 + w * 32;

  int koff[2], kldso[2], voff[2], vldso[2];
  #pragma unroll
  for (int c = 0; c < 2; ++c){
    int o = c * 8192 + t * 16;
    { int row = o >> 8, col = o & 255; int cs = col ^ ((row & 15) << 4);
      kldso[c] = o >> 1;  koff[c] = row * ND + (cs >> 1); }
    { int row = o >> 7, col = o & 127; int cs = col ^ ((row & 7) << 4);
      vldso[c] = o >> 1;  voff[c] = row * NS + (cs >> 1); }
  }
  const u16* Kbase = Ka + (size_t)bh * NS * ND;
  const u16* Vbase = Vt + (size_t)bh * ND * NS;

  // prologue vmem order: qf(8) -> K0(2) -> V0(2) -> K1(2); vmcnt(4) retires qf+K0
  bf16x8 qf[8];
  #pragma unroll
  for (int kk = 0; kk < 8; ++kk)
    qf[kk] = *(const bf16x8*)(Qa + ((size_t)bh * NS + q0 + l31) * ND + kk * 16 + hi * 8);

  #pragma unroll
  for (int c = 0; c < 2; ++c) gl_lds16(Kbase + koff[c], Ks0 + kldso[c]);
  #pragma unroll
  for (int c = 0; c < 2; ++c) gl_lds16(Vbase + voff[c], Vs0 + vldso[c]);
  #pragma unroll
  for (int c = 0; c < 2; ++c) gl_lds16(Kbase + 64 * ND + koff[c], Ks1 + kldso[c]);

  // hoisted LDS read byte-offsets
  int krd[2][8], vrd[4][4];
  #pragma unroll
  for (int t2 = 0; t2 < 2; ++t2){
    const int row = t2 * 32 + l31, sw = (row & 15) << 4;
    #pragma unroll
    for (int kk = 0; kk < 8; ++kk)
      krd[t2][kk] = row * 256 + ((kk * 32 + hi * 16) ^ sw);
  }
  #pragma unroll
  for (int dt = 0; dt < 4; ++dt){
    const int row = dt * 32 + l31, sw = (row & 7) << 4;
    #pragma unroll
    for (int kk = 0; kk < 4; ++kk)
      vrd[kk][dt] = row * 128 + ((kk * 32 + hi * 16) ^ sw);
  }

  asm volatile("s_waitcnt vmcnt(4)" ::: "memory");   // qf + K0 done; V0,K1 in flight
  __builtin_amdgcn_s_barrier();

  f32x16 scA[2], scB[2];
  scA[0] = (f32x16)(0.f); scA[1] = (f32x16)(0.f);
  {
    const char* Kl = (const char*)Ks0;
    #pragma unroll
    for (int t2 = 0; t2 < 2; ++t2)
      #pragma unroll
      for (int kk = 0; kk < 8; ++kk){
        bf16x8 kf = *(const bf16x8*)(Kl + krd[t2][kk]);
        scA[t2] = __builtin_amdgcn_mfma_f32_32x32x16_bf16(kf, qf[kk], scA[t2], 0, 0, 0);
      }
  }
  __builtin_amdgcn_s_barrier();   // K0 buffer free for restaging

  f32x16 acc[4] = {};
  float lrow = 0.f;

  for (int kt = 0; kt < 30; kt += 2){
    AT_BODY(kt,     scA, scB, Ks0, Vs1, (const char*)Ks1, (const char*)Vs0, 1, 1, "4", 0);
    AT_BODY(kt + 1, scB, scA, Ks1, Vs0, (const char*)Ks0, (const char*)Vs1, 1, 1, "4", 0);
  }
  AT_BODY(30, scA, scB, Ks0, Vs1, (const char*)Ks1, (const char*)Vs0, 0, 1, "2", 0);
  AT_BODY(31, scB, scA, Ks1, Vs0, (const char*)Ks0, (const char*)Vs1, 0, 0, "0", 1);

  // epilogue: one cross-half reduce of lrow, then O[q][d] = acc / l -> ctx [B][S][E]
  lrow += __shfl_xor(lrow, 32);
  const float inv = 1.0f / lrow;
  const int b = bh >> 4, h = bh & 15;
  const int s = q0 + l31;
  #pragma unroll
  for (int dt = 0; dt < 4; ++dt)
    #pragma unroll
    for (int a2 = 0; a2 < 4; ++a2){
      const int d0 = dt * 32 + 8 * a2 + 4 * hi;
      ushort4 o;
      o.x = f2bf(acc[dt][4*a2+0] * inv);
      o.y = f2bf(acc[dt][4*a2+1] * inv);
      o.z = f2bf(acc[dt][4*a2+2] * inv);
      o.w = f2bf(acc[dt][4*a2+3] * inv);
      *(ushort4*)(ctx + ((size_t)(b * NS + s)) * NE + h * ND + d0) = o;
    }
}

__global__ __launch_bounds__(512, 2) void k_attn(const u16* __restrict__ Qa, const u16* __restrict__ Ka,
                                                 const u16* __restrict__ Vt, u16* __restrict__ ctx)
{
  __shared__ __align__(16) u16 Ks[2][64 * 128];  // [kv][d], 256B rows, swz (row&15)<<4
  __shared__ __align__(16) u16 Vs[2][128 * 64];  // [d][kv], 128B rows, swz (row&7)<<4
  // runtime probe of v_permlane32_swap_b32 direction (wave-uniform)
  const int lane = threadIdx.x & 63;
  u32 xx = (u32)lane, yy = 64u + (u32)lane;
  asm volatile("v_permlane32_swap_b32 %0, %1" : "+v"(xx), "+v"(yy));
  const bool isD1 = (xx == (u32)(lane < 32 ? lane : lane + 32));
  if (isD1) attn_impl<true >(Qa, Ka, Vt, ctx, &Ks[0][0], &Ks[1][0], &Vs[0][0], &Vs[1][0]);
  else      attn_impl<false>(Qa, Ka, Vt, ctx, &Ks[0][0], &Ks[1][0], &Vs[0][0], &Vs[1][0]);
}

extern "C" void kernel_launch(void* const* d_in, const int* in_sizes, int n_in,
                              void* d_out, int out_size, void* d_ws, size_t ws_size,
                              hipStream_t stream)
{
  const float* x  = (const float*)d_in[0];
  const float* Wq = (const float*)d_in[1];
  const float* bq = (const float*)d_in[2];
  const float* Wk = (const float*)d_in[3];
  const float* bk = (const float*)d_in[4];
  const float* Wv = (const float*)d_in[5];
  const float* bv = (const float*)d_in[6];
  const float* Wo = (const float*)d_in[7];
  const float* bo = (const float*)d_in[8];

  char* ws = (char*)d_ws;
  u16*   xbf  = (u16*)(ws);                      // 16 MiB
  u16*   wqb  = (u16*)(ws + 16777216);           // 8 MiB each; wq,wk,wv CONTIGUOUS (fused W)
  u16*   wkb  = (u16*)(ws + 25165824);
  u16*   wvb  = (u16*)(ws + 33554432);
  u16*   wob  = (u16*)(ws + 41943040);
  float* cosT = (float*)(ws + 50331648);         // 1 MiB each
  float* sinT = (float*)(ws + 51380224);
  u16*   Qa   = (u16*)(ws + 52428800);           // 16 MiB
  u16*   Ka   = (u16*)(ws + 69206016);           // 16 MiB
  u16*   Vt   = (u16*)(ws + 85983232);           // 16 MiB, written transposed by k_gemm_qkv
  u16*   ctx  = xbf;   // alias: x dead after the projection GEMM

  const float sl = 0.08838834764831845f * 1.4426950408889634f;  // (1/sqrt(128)) * log2(e)

  k_prep<<<2048, 256, 0, stream>>>(x, Wq, Wk, Wv, Wo, xbf, wqb, wkb, wvb, wob, cosT, sinT);

  k_gemm_qkv<<<768, 512, 0, stream>>>(xbf, wqb, bq, bk, bv, cosT, sinT, sl, Qa, Ka, Vt);

  k_attn<<<256, 512, 0, stream>>>(Qa, Ka, Vt, ctx);

  k_gemm_o<<<256, 512, 0, stream>>>(ctx, wob, bo, (float*)d_out);
}